// Round 10
// baseline (623.358 us; speedup 1.0000x reference)
//
#include <hip/hip_runtime.h>
#include <hip/hip_bf16.h>
#include <math.h>

#define NQd 100
#define BSd 8
#define NPTd 17
#define DIMd 256
#define NHd 8
#define DHd 32
#define DFFd 1024
#define NTOK (NQd*BSd*NPTd)        // 13600
#define LENIN 11253
#define MTOK (BSd*LENIN)           // 90024

typedef __attribute__((ext_vector_type(8))) short bf16x8;
typedef __attribute__((ext_vector_type(4))) short bf16x4s;
typedef __attribute__((ext_vector_type(4))) float f32x4;

__device__ inline short f2bs(float f) {
    __hip_bfloat16 h = __float2bfloat16(f);
    return *reinterpret_cast<short*>(&h);
}
__device__ inline float bs2f(short s) {
    return __uint_as_float(((unsigned)(unsigned short)s) << 16);
}

// ---------------------------------------------------------------------------
// bf16 MFMA GEMM, 128x128 tile, 4 waves, 16x16x32 frags, BK=32.
// 3-deep pipeline: 2 register sets + 2 LDS buffers; a tile's global loads are
// issued TWO iterations before its ds_write (≈2 MFMA phases of latency cover).
// AMODE: 0 = A bf16 direct; 1 = A fp32; 2 = A fp32 + add (addMode: 0 none,
// 1 always, 2 only when n0<512 — fused QKV); 3 = A fp32, y-order row map.
// ---------------------------------------------------------------------------
template<int AMODE, bool RELU, bool OUT_BF16>
__global__ __launch_bounds__(256)
void gemm_mfma(const void* __restrict__ Av, const float* __restrict__ Aadd,
               const __hip_bfloat16* __restrict__ W, const float* __restrict__ bias,
               void* __restrict__ Cv, int M, int N, int K, int ldc, int col0,
               int addMode) {
    __shared__ __hip_bfloat16 LA[2][4][128][8];
    __shared__ __hip_bfloat16 LW[2][4][128][8];
    const int tid = threadIdx.x;
    const int lane = tid & 63, wave = tid >> 6;
    const int wr = wave >> 1, wc = wave & 1;
    const int m0 = blockIdx.y * 128, n0 = blockIdx.x * 128;
    const int l15 = lane & 15, lg = lane >> 4;
    const int srow = tid >> 2, koct = tid & 3;

    // --- per-thread A/W row pointers (fixed across K) ---
    const int gmA = m0 + srow, gmB = m0 + srow + 64;
    const bool ok0 = gmA < M, ok1 = gmB < M;
    int src0 = gmA, src1 = gmB;
    if (AMODE == 3) {
        src0 = (gmA % 100) * 136 + gmA / 100;
        src1 = (gmB % 100) * 136 + gmB / 100;
    }
    const __hip_bfloat16* pAb0 = nullptr; const __hip_bfloat16* pAb1 = nullptr;
    const float* pAf0 = nullptr; const float* pAf1 = nullptr;
    const float* pD0 = nullptr;  const float* pD1 = nullptr;
    bool doAdd = false;
    if (AMODE == 0) {
        pAb0 = (const __hip_bfloat16*)Av + (size_t)src0 * K + koct * 8;
        pAb1 = (const __hip_bfloat16*)Av + (size_t)src1 * K + koct * 8;
    } else {
        pAf0 = (const float*)Av + (size_t)src0 * K + koct * 8;
        pAf1 = (const float*)Av + (size_t)src1 * K + koct * 8;
        if (AMODE == 2) {
            doAdd = (addMode == 1) || (addMode == 2 && n0 < 512);
            pD0 = Aadd + (size_t)src0 * K + koct * 8;
            pD1 = Aadd + (size_t)src1 * K + koct * 8;
        }
    }
    const __hip_bfloat16* pW0 = W + (size_t)(n0 + srow) * K + koct * 8;
    const __hip_bfloat16* pW1 = W + (size_t)(n0 + srow + 64) * K + koct * 8;

    // --- register sets (static names; rule #20) ---
    bf16x8 aB0[2], aB1[2], wS0[2], wS1[2];
    float4 aF0[2][2], aF1[2][2], dF0[2][2], dF1[2][2];
    const f32x4 z4 = (f32x4){0.f, 0.f, 0.f, 0.f};

#define LOAD_SET(S, kt) do {                                                   \
    const int k0_ = (kt) * 32;                                                 \
    if (AMODE == 0) {                                                          \
        aB##S[0] = ok0 ? *(const bf16x8*)(pAb0 + k0_) : (bf16x8){0,0,0,0,0,0,0,0}; \
        aB##S[1] = ok1 ? *(const bf16x8*)(pAb1 + k0_) : (bf16x8){0,0,0,0,0,0,0,0}; \
    } else {                                                                   \
        aF##S[0][0] = ok0 ? *(const float4*)(pAf0 + k0_)     : *(const float4*)&z4; \
        aF##S[0][1] = ok0 ? *(const float4*)(pAf0 + k0_ + 4) : *(const float4*)&z4; \
        aF##S[1][0] = ok1 ? *(const float4*)(pAf1 + k0_)     : *(const float4*)&z4; \
        aF##S[1][1] = ok1 ? *(const float4*)(pAf1 + k0_ + 4) : *(const float4*)&z4; \
        if (AMODE == 2 && doAdd) {                                             \
            dF##S[0][0] = ok0 ? *(const float4*)(pD0 + k0_)     : *(const float4*)&z4; \
            dF##S[0][1] = ok0 ? *(const float4*)(pD0 + k0_ + 4) : *(const float4*)&z4; \
            dF##S[1][0] = ok1 ? *(const float4*)(pD1 + k0_)     : *(const float4*)&z4; \
            dF##S[1][1] = ok1 ? *(const float4*)(pD1 + k0_ + 4) : *(const float4*)&z4; \
        }                                                                      \
    }                                                                          \
    wS##S[0] = *(const bf16x8*)(pW0 + k0_);                                    \
    wS##S[1] = *(const bf16x8*)(pW1 + k0_);                                    \
} while (0)

#define CVT_ROW(S, it) ((AMODE == 2 && doAdd) ?                                \
    (bf16x8){f2bs(aF##S[it][0].x + dF##S[it][0].x), f2bs(aF##S[it][0].y + dF##S[it][0].y), \
             f2bs(aF##S[it][0].z + dF##S[it][0].z), f2bs(aF##S[it][0].w + dF##S[it][0].w), \
             f2bs(aF##S[it][1].x + dF##S[it][1].x), f2bs(aF##S[it][1].y + dF##S[it][1].y), \
             f2bs(aF##S[it][1].z + dF##S[it][1].z), f2bs(aF##S[it][1].w + dF##S[it][1].w)} : \
    (bf16x8){f2bs(aF##S[it][0].x), f2bs(aF##S[it][0].y), f2bs(aF##S[it][0].z), f2bs(aF##S[it][0].w), \
             f2bs(aF##S[it][1].x), f2bs(aF##S[it][1].y), f2bs(aF##S[it][1].z), f2bs(aF##S[it][1].w)})

#define WRITE_SET(S, buf) do {                                                 \
    if (AMODE == 0) {                                                          \
        *(bf16x8*)&LA[buf][koct][srow][0]      = aB##S[0];                     \
        *(bf16x8*)&LA[buf][koct][srow + 64][0] = aB##S[1];                     \
    } else {                                                                   \
        *(bf16x8*)&LA[buf][koct][srow][0]      = CVT_ROW(S, 0);                \
        *(bf16x8*)&LA[buf][koct][srow + 64][0] = CVT_ROW(S, 1);                \
    }                                                                          \
    *(bf16x8*)&LW[buf][koct][srow][0]      = wS##S[0];                         \
    *(bf16x8*)&LW[buf][koct][srow + 64][0] = wS##S[1];                         \
} while (0)

    f32x4 acc[4][4];
#pragma unroll
    for (int i = 0; i < 4; ++i)
#pragma unroll
        for (int j = 0; j < 4; ++j) acc[i][j] = z4;

#define DO_TILE(buf)                                                           \
    {                                                                          \
        bf16x8 af[4], bfr[4];                                                  \
        _Pragma("unroll")                                                      \
        for (int f = 0; f < 4; ++f) {                                          \
            af[f]  = *(const bf16x8*)&LA[buf][lg][wr * 64 + f * 16 + l15][0];  \
            bfr[f] = *(const bf16x8*)&LW[buf][lg][wc * 64 + f * 16 + l15][0];  \
        }                                                                      \
        _Pragma("unroll")                                                      \
        for (int fm = 0; fm < 4; ++fm)                                         \
            _Pragma("unroll")                                                  \
            for (int fn = 0; fn < 4; ++fn)                                     \
                acc[fm][fn] = __builtin_amdgcn_mfma_f32_16x16x32_bf16(af[fm], bfr[fn], acc[fm][fn], 0, 0, 0); \
    }

    const int NT = K >> 5;     // all K here are 256 or 1024 -> NT >= 8
    LOAD_SET(0, 0);
    WRITE_SET(0, 0);
    LOAD_SET(1, 1);
    LOAD_SET(0, 2);
    __syncthreads();
    for (int t = 0; t < NT; t += 2) {
        // even: compute buf0 (tile t); commit S1 (tile t+1) -> buf1; load t+3 -> S1
        if (t + 1 < NT) WRITE_SET(1, 1);
        if (t + 3 < NT) LOAD_SET(1, t + 3);
        DO_TILE(0);
        __syncthreads();
        if (t + 1 >= NT) break;
        // odd: compute buf1 (tile t+1); commit S0 (tile t+2) -> buf0; load t+4 -> S0
        if (t + 2 < NT) WRITE_SET(0, 0);
        if (t + 4 < NT) LOAD_SET(0, t + 4);
        DO_TILE(1);
        __syncthreads();
    }

#pragma unroll
    for (int fm = 0; fm < 4; ++fm) {
        const int row = m0 + wr * 64 + fm * 16 + lg * 4;
#pragma unroll
        for (int fn = 0; fn < 4; ++fn) {
            const int coln = n0 + wc * 64 + fn * 16 + l15;
            const float bsv = bias[coln];
#pragma unroll
            for (int r = 0; r < 4; ++r) {
                const int gr = row + r;
                if (gr >= M) continue;
                float v = acc[fm][fn][r] + bsv;
                if (RELU) v = fmaxf(v, 0.f);
                if (OUT_BF16)
                    ((__hip_bfloat16*)Cv)[(size_t)gr * ldc + col0 + coln] = __float2bfloat16(v);
                else
                    ((float*)Cv)[(size_t)gr * ldc + col0 + coln] = v;
            }
        }
    }
#undef LOAD_SET
#undef CVT_ROW
#undef WRITE_SET
#undef DO_TILE
}

// ---------------------------------------------------------------------------
// Fused weight conversion fp32 -> bf16 into one packed buffer.
// ---------------------------------------------------------------------------
__global__ void cvt_weights(const float* w0, const float* w1, const float* w2,
                            const float* w3, const float* w4, const float* w5,
                            const float* w6, const float* w7, const float* w8,
                            const float* w9, __hip_bfloat16* dst) {
    int idx = blockIdx.x * 256 + threadIdx.x;
    float v;
    if      (idx <  196608) v = w0[idx];
    else if (idx <  262144) v = w1[idx -  196608];
    else if (idx <  458752) v = w2[idx -  262144];
    else if (idx <  524288) v = w3[idx -  458752];
    else if (idx <  589824) v = w4[idx -  524288];
    else if (idx <  622592) v = w5[idx -  589824];
    else if (idx <  688128) v = w6[idx -  622592];
    else if (idx <  753664) v = w7[idx -  688128];
    else if (idx < 1015808) v = w8[idx -  753664];
    else                    v = w9[idx - 1015808];
    dst[idx] = __float2bfloat16(v);
}

// ---------------------------------------------------------------------------
// Row gather mode 2 only (deform q order): dst[t] = X[r] + qpos[r], bf16.
// ---------------------------------------------------------------------------
__global__ void gather_rows_b(const float* __restrict__ src, const float* __restrict__ add,
                              __hip_bfloat16* __restrict__ dst) {
    int t = blockIdx.x, c = threadIdx.x;
    int b = t / 1700, jj = t % 1700;
    int q = jj / 17, p = jj % 17;
    int r = q * 136 + b * 17 + p;
    float v = src[(size_t)r * 256 + c] + add[(size_t)r * 256 + c];
    dst[(size_t)t * 256 + c] = __float2bfloat16(v);
}

// ---------------------------------------------------------------------------
// MHA S=17 (group attention). qkv bf16 rows t*768 (Q|K|V). block=(group, head)
// ---------------------------------------------------------------------------
__global__ void attn17(const __hip_bfloat16* __restrict__ qkv, __hip_bfloat16* __restrict__ out) {
    const int g = blockIdx.x, h = blockIdx.y;
    __shared__ float q[17][32], k[17][32], v[17][32], s[17][18];
    const int tid = threadIdx.x;  // 256
    for (int idx = tid; idx < 17 * 32; idx += 256) {
        int i = idx >> 5, d = idx & 31;
        size_t row = (size_t)(g * 17 + i) * 768 + h * 32 + d;
        q[i][d] = bs2f(*(const short*)&qkv[row]);
        k[i][d] = bs2f(*(const short*)&qkv[row + 256]);
        v[i][d] = bs2f(*(const short*)&qkv[row + 512]);
    }
    __syncthreads();
    for (int idx = tid; idx < 17 * 17; idx += 256) {
        int i = idx / 17, j = idx % 17;
        float acc = 0.f;
#pragma unroll
        for (int d = 0; d < 32; ++d) acc += q[i][d] * k[j][d];
        s[i][j] = acc * 0.17677669529663688f;
    }
    __syncthreads();
    if (tid < 17) {
        float m = -1e30f;
        for (int j = 0; j < 17; ++j) m = fmaxf(m, s[tid][j]);
        float sum = 0.f;
        for (int j = 0; j < 17; ++j) { float e = __expf(s[tid][j] - m); s[tid][j] = e; sum += e; }
        float inv = 1.f / sum;
        for (int j = 0; j < 17; ++j) s[tid][j] *= inv;
    }
    __syncthreads();
    for (int idx = tid; idx < 17 * 32; idx += 256) {
        int i = idx >> 5, d = idx & 31;
        float acc = 0.f;
        for (int j = 0; j < 17; ++j) acc += s[i][j] * v[j][d];
        out[(size_t)(g * 17 + i) * 256 + h * 32 + d] = __float2bfloat16(acc);
    }
}

// ---------------------------------------------------------------------------
// MHA S=100: thread-per-query online softmax, bf16 qkv input.
// ---------------------------------------------------------------------------
__global__ __launch_bounds__(128)
void attn100(const __hip_bfloat16* __restrict__ qkv, __hip_bfloat16* __restrict__ out) {
    const int g = blockIdx.x, h = blockIdx.y;
    __shared__ float Ks[100][32], Vs[100][32];
    const int tid = threadIdx.x;  // 128
    for (int idx = tid; idx < 800; idx += 128) {
        int j = idx >> 3, qd = (idx & 7) * 4;
        const __hip_bfloat16* base = qkv + (size_t)(g * 100 + j) * 768 + h * 32;
        bf16x4s kv = *(const bf16x4s*)(base + 256 + qd);
        bf16x4s vv = *(const bf16x4s*)(base + 512 + qd);
        Ks[j][qd] = bs2f(kv.x); Ks[j][qd+1] = bs2f(kv.y); Ks[j][qd+2] = bs2f(kv.z); Ks[j][qd+3] = bs2f(kv.w);
        Vs[j][qd] = bs2f(vv.x); Vs[j][qd+1] = bs2f(vv.y); Vs[j][qd+2] = bs2f(vv.z); Vs[j][qd+3] = bs2f(vv.w);
    }
    __syncthreads();
    if (tid >= 100) return;
    const __hip_bfloat16* qp = qkv + (size_t)(g * 100 + tid) * 768 + h * 32;
    float q[32];
#pragma unroll
    for (int d4 = 0; d4 < 32; d4 += 4) {
        bf16x4s v = *(const bf16x4s*)(qp + d4);
        q[d4] = bs2f(v.x); q[d4 + 1] = bs2f(v.y); q[d4 + 2] = bs2f(v.z); q[d4 + 3] = bs2f(v.w);
    }
    float m = -1e30f, l = 0.f, o[32];
#pragma unroll
    for (int d = 0; d < 32; ++d) o[d] = 0.f;
    for (int j = 0; j < 100; ++j) {
        float s = 0.f;
#pragma unroll
        for (int d = 0; d < 32; ++d) s += q[d] * Ks[j][d];
        s *= 0.17677669529663688f;
        float nm = fmaxf(m, s);
        float f = __expf(m - nm), p = __expf(s - nm);
        l = l * f + p;
#pragma unroll
        for (int d = 0; d < 32; ++d) o[d] = o[d] * f + p * Vs[j][d];
        m = nm;
    }
    float inv = 1.f / l;
    __hip_bfloat16* op = out + (size_t)(g * 100 + tid) * 256 + h * 32;
#pragma unroll
    for (int d = 0; d < 32; ++d) op[d] = __float2bfloat16(o[d] * inv);
}

// ---------------------------------------------------------------------------
// Deformable sampling: bf16 value input. block = 4 tokens, 256 threads.
// ---------------------------------------------------------------------------
#define TPB 4
__global__ __launch_bounds__(256)
void deform_sample(const __hip_bfloat16* __restrict__ value, const float* __restrict__ off,
                   const float* __restrict__ aw, const float* __restrict__ ref,
                   __hip_bfloat16* __restrict__ out) {
    const int t0 = blockIdx.x * TPB;
    const int tid = threadIdx.x;
    __shared__ float raw[TPB][128];
    __shared__ float wgt[TPB][128];
    __shared__ int   cidx[TPB][128][4];
    __shared__ float cw[TPB][128][4];

    for (int idx = tid; idx < TPB * 128; idx += 256) {
        int tk = idx >> 7, i = idx & 127;
        raw[tk][i] = aw[(size_t)(t0 + tk) * 128 + i];
    }
    __syncthreads();
    if (tid < TPB * 8) {
        int tk = tid >> 3, h = tid & 7;
        float m = -1e30f;
        for (int i = 0; i < 16; ++i) m = fmaxf(m, raw[tk][h * 16 + i]);
        float sum = 0.f;
        float e[16];
        for (int i = 0; i < 16; ++i) { e[i] = __expf(raw[tk][h * 16 + i] - m); sum += e[i]; }
        float inv = 1.f / sum;
        for (int i = 0; i < 16; ++i) wgt[tk][h * 16 + i] = e[i] * inv;
    }
    __syncthreads();

    const int Hs[4] = {92, 46, 23, 12};
    const int Sts[4] = {0, 8464, 10580, 11109};
    for (int s = tid; s < TPB * 128; s += 256) {
        int tk = s >> 7, sid = s & 127;
        int t = t0 + tk;
        int b = t / 1700, jj = t % 1700;
        int q = jj / 17, p = jj % 17;
        int l = (sid >> 2) & 3;
        int HW = Hs[l];
        float HWf = (float)HW;
        const float* refp = ref + (size_t)((q * 8 + b) * 17 + p) * 8;
        float rx = refp[l * 2], ry = refp[l * 2 + 1];
        float ox = off[(size_t)t * 256 + sid * 2];
        float oy = off[(size_t)t * 256 + sid * 2 + 1];
        float x = (rx + ox / HWf) * HWf - 0.5f;
        float y = (ry + oy / HWf) * HWf - 0.5f;
        float x0f = floorf(x), y0f = floorf(y);
        float wx = x - x0f, wy = y - y0f;
        int xi = (int)x0f, yi = (int)y0f;
        float wg = wgt[tk][sid];
#pragma unroll
        for (int c = 0; c < 4; ++c) {
            int cy = c >> 1, cx = c & 1;
            int yy = yi + cy, xx = xi + cx;
            bool ok = (xx >= 0) && (xx < HW) && (yy >= 0) && (yy < HW);
            int yc = min(max(yy, 0), HW - 1);
            int xc = min(max(xx, 0), HW - 1);
            cidx[tk][sid][c] = Sts[l] + yc * HW + xc;
            float w = (cy ? wy : 1.f - wy) * (cx ? wx : 1.f - wx);
            cw[tk][sid][c] = ok ? wg * w : 0.f;
        }
    }
    __syncthreads();

    const int tk = tid >> 6, lane = tid & 63;
    const int h = lane >> 3, d4 = (lane & 7) * 4;
    const int t = t0 + tk;
    const int b = t / 1700;
    const __hip_bfloat16* vb = value + (size_t)b * LENIN * 256 + h * 32 + d4;
    float4 acc = make_float4(0.f, 0.f, 0.f, 0.f);
    for (int s16 = 0; s16 < 16; ++s16) {
        int sid = h * 16 + s16;
#pragma unroll
        for (int c = 0; c < 4; ++c) {
            int idx = cidx[tk][sid][c];
            float w = cw[tk][sid][c];
            bf16x4s v = *(const bf16x4s*)(vb + (size_t)idx * 256);
            acc.x += w * bs2f(v.x); acc.y += w * bs2f(v.y);
            acc.z += w * bs2f(v.z); acc.w += w * bs2f(v.w);
        }
    }
    __hip_bfloat16* op = out + (size_t)t * 256 + h * 32 + d4;
    op[0] = __float2bfloat16(acc.x);
    op[1] = __float2bfloat16(acc.y);
    op[2] = __float2bfloat16(acc.z);
    op[3] = __float2bfloat16(acc.w);
}

// ---------------------------------------------------------------------------
// Residual + LayerNorm, one wave per row, shuffle reduce. proj is bf16.
// ---------------------------------------------------------------------------
__global__ __launch_bounds__(256)
void res_ln(const float* __restrict__ res, const __hip_bfloat16* __restrict__ proj,
            const float* __restrict__ g, const float* __restrict__ be,
            float* __restrict__ out, __hip_bfloat16* __restrict__ outb, int mode) {
    const int wave = threadIdx.x >> 6, lane = threadIdx.x & 63;
    const int r = blockIdx.x * 4 + wave;
    int t;
    if (mode == 0) t = r;
    else if (mode == 1) { int q = r / 136, m = r % 136; t = m * 100 + q; }
    else { int q = r / 136, rem = r % 136; int b = rem / 17, p = rem % 17; t = b * 1700 + q * 17 + p; }
    const int c4 = lane * 4;
    float4 a = *(const float4*)&res[(size_t)r * 256 + c4];
    bf16x4s pb = *(const bf16x4s*)&proj[(size_t)t * 256 + c4];
    float v[4] = {a.x + bs2f(pb.x), a.y + bs2f(pb.y), a.z + bs2f(pb.z), a.w + bs2f(pb.w)};
    float s = v[0] + v[1] + v[2] + v[3];
#pragma unroll
    for (int off = 32; off > 0; off >>= 1) s += __shfl_xor(s, off);
    float mean = s * (1.f / 256.f);
    float d[4], ss = 0.f;
#pragma unroll
    for (int i = 0; i < 4; ++i) { d[i] = v[i] - mean; ss += d[i] * d[i]; }
#pragma unroll
    for (int off = 32; off > 0; off >>= 1) ss += __shfl_xor(ss, off);
    float rs = rsqrtf(ss * (1.f / 256.f) + 1e-5f);
    float4 gv = *(const float4*)&g[c4];
    float4 bv = *(const float4*)&be[c4];
    float o0 = d[0] * rs * gv.x + bv.x;
    float o1 = d[1] * rs * gv.y + bv.y;
    float o2 = d[2] * rs * gv.z + bv.z;
    float o3 = d[3] * rs * gv.w + bv.w;
    *(float4*)&out[(size_t)r * 256 + c4] = make_float4(o0, o1, o2, o3);
    if (outb) {
        bf16x4s ob = {f2bs(o0), f2bs(o1), f2bs(o2), f2bs(o3)};
        *(bf16x4s*)&outb[(size_t)r * 256 + c4] = ob;
    }
}

// ---------------------------------------------------------------------------
extern "C" void kernel_launch(void* const* d_in, const int* in_sizes, int n_in,
                              void* d_out, int out_size, void* d_ws, size_t ws_size,
                              hipStream_t stream) {
    const float* tgt    = (const float*)d_in[0];
    const float* qpos   = (const float*)d_in[1];
    const float* ref    = (const float*)d_in[2];
    const float* memory = (const float*)d_in[3];
    const float* w_in_w = (const float*)d_in[4];
    const float* b_in_w = (const float*)d_in[5];
    const float* w_out_w= (const float*)d_in[6];
    const float* b_out_w= (const float*)d_in[7];
    const float* w_in_a = (const float*)d_in[8];
    const float* b_in_a = (const float*)d_in[9];
    const float* w_out_a= (const float*)d_in[10];
    const float* b_out_a= (const float*)d_in[11];
    const float* w_off  = (const float*)d_in[12];
    const float* b_off  = (const float*)d_in[13];
    const float* w_aw   = (const float*)d_in[14];
    const float* b_aw   = (const float*)d_in[15];
    const float* w_val  = (const float*)d_in[16];
    const float* b_val  = (const float*)d_in[17];
    const float* w_oc   = (const float*)d_in[18];
    const float* b_oc   = (const float*)d_in[19];
    const float* g_w    = (const float*)d_in[20];
    const float* be_w   = (const float*)d_in[21];
    const float* g_a    = (const float*)d_in[22];
    const float* be_a   = (const float*)d_in[23];
    const float* g1     = (const float*)d_in[24];
    const float* be1    = (const float*)d_in[25];
    const float* g2     = (const float*)d_in[26];
    const float* be2    = (const float*)d_in[27];
    const float* w1     = (const float*)d_in[28];
    const float* b1     = (const float*)d_in[29];
    const float* w2     = (const float*)d_in[30];
    const float* b2     = (const float*)d_in[31];

    float* X  = (float*)d_out;                       // persistent x, 13600x256 fp32
    float* ws = (float*)d_ws;
    float* R1 = ws;                                  // 23,046,144 f (qkv bf16 / value bf16 / H bf16)
    float* R2 = R1 + (size_t)MTOK * 256;             //  3,481,600 f (off fp32 / proj bf16)
    float* R3 = R2 + (size_t)NTOK * 256;             //  1,740,800 f (bf16 attn/deform outs)
    float* R6 = R3 + (size_t)NTOK * 128;             //  1,740,800 f (raw attn weights fp32)
    float* QBF= R6 + (size_t)NTOK * 128;             //  1,740,800 f (bf16 deform-q / ffn in)
    float* WBF= QBF+ (size_t)NTOK * 128;             //    638,976 f (packed bf16 weights)

    __hip_bfloat16* R1b = (__hip_bfloat16*)R1;
    __hip_bfloat16* R2b = (__hip_bfloat16*)R2;
    __hip_bfloat16* R3b = (__hip_bfloat16*)R3;
    __hip_bfloat16* Qb  = (__hip_bfloat16*)QBF;
    __hip_bfloat16* Wb  = (__hip_bfloat16*)WBF;
    __hip_bfloat16* Hb  = (__hip_bfloat16*)R1;       // ffn hidden alias
    __hip_bfloat16* Vb  = (__hip_bfloat16*)R1;       // value alias

    __hip_bfloat16* w_in_w_b  = Wb;                  // 768x256
    __hip_bfloat16* w_out_w_b = Wb +  196608;        // 256x256
    __hip_bfloat16* w_in_a_b  = Wb +  262144;        // 768x256
    __hip_bfloat16* w_out_a_b = Wb +  458752;        // 256x256
    __hip_bfloat16* w_off_b   = Wb +  524288;        // 256x256
    __hip_bfloat16* w_aw_b    = Wb +  589824;        // 128x256
    __hip_bfloat16* w_val_b   = Wb +  622592;        // 256x256
    __hip_bfloat16* w_oc_b    = Wb +  688128;        // 256x256
    __hip_bfloat16* w1_b      = Wb +  753664;        // 1024x256
    __hip_bfloat16* w2_b      = Wb + 1015808;        // 256x1024

    cvt_weights<<<4992, 256, 0, stream>>>(w_in_w, w_out_w, w_in_a, w_out_a, w_off,
                                          w_aw, w_val, w_oc, w1, w2, Wb);

    const int MY = (NTOK + 127) / 128;   // 107

    // ---- Phase 1: fused QKV projection (QK: tgt+qpos, V: tgt) ----
    gemm_mfma<2, false, true><<<dim3(6, MY), 256, 0, stream>>>(
        tgt, qpos, w_in_w_b, b_in_w, R1b, NTOK, 768, 256, 768, 0, 2);
    attn17<<<dim3(800, 8), 256, 0, stream>>>(R1b, R3b);
    gemm_mfma<0, false, true><<<dim3(2, MY), 256, 0, stream>>>(
        R3b, nullptr, w_out_w_b, b_out_w, R2b, NTOK, 256, 256, 256, 0, 0);
    res_ln<<<NTOK / 4, 256, 0, stream>>>(tgt, R2b, g_w, be_w, X, nullptr, 0);

    // ---- Phase 2: query attention, gather fused (y-order A-map) ----
    gemm_mfma<3, false, true><<<dim3(6, MY), 256, 0, stream>>>(
        X, nullptr, w_in_a_b, b_in_a, R1b, NTOK, 768, 256, 768, 0, 0);
    attn100<<<dim3(136, 8), 128, 0, stream>>>(R1b, R3b);
    gemm_mfma<0, false, true><<<dim3(2, MY), 256, 0, stream>>>(
        R3b, nullptr, w_out_a_b, b_out_a, R2b, NTOK, 256, 256, 256, 0, 0);
    res_ln<<<NTOK / 4, 256, 0, stream>>>(X, R2b, g_a, be_a, X, nullptr, 1);

    // ---- Phase 3: deformable attention ----
    gemm_mfma<1, false, true><<<dim3(2, (MTOK + 127) / 128), 256, 0, stream>>>(
        memory, nullptr, w_val_b, b_val, Vb, MTOK, 256, 256, 256, 0, 0);
    gather_rows_b<<<NTOK, 256, 0, stream>>>(X, qpos, Qb);
    gemm_mfma<0, false, false><<<dim3(2, MY), 256, 0, stream>>>(
        Qb, nullptr, w_off_b, b_off, R2, NTOK, 256, 256, 256, 0, 0);
    gemm_mfma<0, false, false><<<dim3(1, MY), 256, 0, stream>>>(
        Qb, nullptr, w_aw_b, b_aw, R6, NTOK, 128, 256, 128, 0, 0);
    deform_sample<<<NTOK / TPB, 256, 0, stream>>>(Vb, R2, R6, ref, R3b);
    gemm_mfma<0, false, true><<<dim3(2, MY), 256, 0, stream>>>(
        R3b, nullptr, w_oc_b, b_oc, R2b, NTOK, 256, 256, 256, 0, 0);
    res_ln<<<NTOK / 4, 256, 0, stream>>>(X, R2b, g1, be1, X, Qb, 2);

    // ---- Phase 4: FFN ----
    gemm_mfma<0, true, true><<<dim3(8, MY), 256, 0, stream>>>(
        Qb, nullptr, w1_b, b1, Hb, NTOK, 1024, 256, 1024, 0, 0);
    gemm_mfma<0, false, true><<<dim3(2, MY), 256, 0, stream>>>(
        Hb, nullptr, w2_b, b2, R2b, NTOK, 256, 1024, 256, 0, 0);
    res_ln<<<NTOK / 4, 256, 0, stream>>>(X, R2b, g2, be2, X, nullptr, 0);
}

// Round 11
// 408.356 us; speedup vs baseline: 1.5265x; 1.5265x over previous
//
#include <hip/hip_runtime.h>
#include <hip/hip_bf16.h>
#include <math.h>

#define NQd 100
#define BSd 8
#define NPTd 17
#define DIMd 256
#define NHd 8
#define DHd 32
#define DFFd 1024
#define NTOK (NQd*BSd*NPTd)        // 13600
#define LENIN 11253
#define MTOK (BSd*LENIN)           // 90024

typedef __attribute__((ext_vector_type(8))) short bf16x8;
typedef __attribute__((ext_vector_type(4))) short bf16x4s;
typedef __attribute__((ext_vector_type(4))) float f32x4;

__device__ inline short f2bs(float f) {
    __hip_bfloat16 h = __float2bfloat16(f);
    return *reinterpret_cast<short*>(&h);
}
__device__ inline float bs2f(short s) {
    return __uint_as_float(((unsigned)(unsigned short)s) << 16);
}

// ---------------------------------------------------------------------------
// bf16 MFMA GEMM, 128x128 tile, 512 thr = 8 waves (2M x 4N), per-wave 64x32.
// acc = 8 f32x4 (32 VGPR) -> ~6 waves/SIMD occupancy.
// A staged via 16 KB double-buffered LDS (raw loads kept in regs, cvt at
// write-time => true prefetch even for fp32 A). W read directly from global
// (all W panels are L2-resident, <=512 KB).
// AMODE: 0 = A bf16; 1 = A fp32; 2 = A fp32 + add (addMode: 1 always,
// 2 only when n0<512 — fused QKV); 3 = A fp32, y-order row map.
// ---------------------------------------------------------------------------
template<int AMODE, bool RELU, bool OUT_BF16>
__global__ __launch_bounds__(512)
void gemm_mfma(const void* __restrict__ Av, const float* __restrict__ Aadd,
               const __hip_bfloat16* __restrict__ W, const float* __restrict__ bias,
               void* __restrict__ Cv, int M, int N, int K, int ldc, int col0,
               int addMode) {
    __shared__ __hip_bfloat16 LA[2][4][128][8];   // [buf][koct][row][8] = 16 KB
    const int tid = threadIdx.x;
    const int lane = tid & 63, wave = tid >> 6;   // 8 waves
    const int wr = wave >> 2, wc = wave & 3;      // 2 x 4
    const int m0 = blockIdx.y * 128, n0 = blockIdx.x * 128;
    const int l15 = lane & 15, lg = lane >> 4;
    const int srow = tid >> 2, koct = tid & 3;    // one A row-slot per thread

    // ---- A source pointer (row map per AMODE) ----
    const int gmA = m0 + srow;
    const bool okA = gmA < M;
    int srcA = gmA;
    if (AMODE == 3) srcA = (gmA % 100) * 136 + gmA / 100;
    const __hip_bfloat16* pAb = nullptr;
    const float* pAf = nullptr; const float* pDf = nullptr;
    bool doAdd = false;
    if (AMODE == 0) {
        pAb = (const __hip_bfloat16*)Av + (size_t)srcA * K + koct * 8;
    } else {
        pAf = (const float*)Av + (size_t)srcA * K + koct * 8;
        if (AMODE == 2) {
            doAdd = (addMode == 1) || (addMode == 2 && n0 < 512);
            pDf = Aadd + (size_t)srcA * K + koct * 8;
        }
    }
    // ---- W fragment pointers (direct global, L2-hit) ----
    const __hip_bfloat16* pW0 = W + (size_t)(n0 + wc * 32 + l15) * K + lg * 8;
    const __hip_bfloat16* pW1 = W + (size_t)(n0 + wc * 32 + 16 + l15) * K + lg * 8;

    // ---- single prefetch register set (raw; cvt deferred to write) ----
    bf16x8 aB;
    float4 aF0, aF1, dD0, dD1;
    auto load_tile = [&](int k0) {
        if (AMODE == 0) {
            aB = okA ? *(const bf16x8*)(pAb + k0) : (bf16x8){0, 0, 0, 0, 0, 0, 0, 0};
        } else {
            aF0 = okA ? *(const float4*)(pAf + k0)     : make_float4(0.f, 0.f, 0.f, 0.f);
            aF1 = okA ? *(const float4*)(pAf + k0 + 4) : make_float4(0.f, 0.f, 0.f, 0.f);
            if (AMODE == 2 && doAdd) {
                dD0 = okA ? *(const float4*)(pDf + k0)     : make_float4(0.f, 0.f, 0.f, 0.f);
                dD1 = okA ? *(const float4*)(pDf + k0 + 4) : make_float4(0.f, 0.f, 0.f, 0.f);
            }
        }
    };
    auto write_tile = [&](int buf) {
        bf16x8 v;
        if (AMODE == 0) {
            v = aB;
        } else if (AMODE == 2 && doAdd) {
            v = (bf16x8){f2bs(aF0.x + dD0.x), f2bs(aF0.y + dD0.y),
                         f2bs(aF0.z + dD0.z), f2bs(aF0.w + dD0.w),
                         f2bs(aF1.x + dD1.x), f2bs(aF1.y + dD1.y),
                         f2bs(aF1.z + dD1.z), f2bs(aF1.w + dD1.w)};
        } else {
            v = (bf16x8){f2bs(aF0.x), f2bs(aF0.y), f2bs(aF0.z), f2bs(aF0.w),
                         f2bs(aF1.x), f2bs(aF1.y), f2bs(aF1.z), f2bs(aF1.w)};
        }
        *(bf16x8*)&LA[buf][koct][srow][0] = v;
    };

    f32x4 acc[4][2];
#pragma unroll
    for (int i = 0; i < 4; ++i) {
        acc[i][0] = (f32x4){0.f, 0.f, 0.f, 0.f};
        acc[i][1] = (f32x4){0.f, 0.f, 0.f, 0.f};
    }

    const int NT = K >> 5;
    load_tile(0);
    write_tile(0);
    __syncthreads();
    for (int t = 0; t < NT; ++t) {
        const int cur = t & 1;
        if (t + 1 < NT) load_tile((t + 1) * 32);       // A prefetch (raw)
        bf16x8 b0 = *(const bf16x8*)(pW0 + t * 32);    // W frags from L2
        bf16x8 b1 = *(const bf16x8*)(pW1 + t * 32);
        bf16x8 af[4];
#pragma unroll
        for (int f = 0; f < 4; ++f)
            af[f] = *(const bf16x8*)&LA[cur][lg][wr * 64 + f * 16 + l15][0];
#pragma unroll
        for (int fm = 0; fm < 4; ++fm) {
            acc[fm][0] = __builtin_amdgcn_mfma_f32_16x16x32_bf16(af[fm], b0, acc[fm][0], 0, 0, 0);
            acc[fm][1] = __builtin_amdgcn_mfma_f32_16x16x32_bf16(af[fm], b1, acc[fm][1], 0, 0, 0);
        }
        if (t + 1 < NT) write_tile(cur ^ 1);           // vmcnt-wait + cvt + ds_write
        __syncthreads();
    }

#pragma unroll
    for (int fm = 0; fm < 4; ++fm) {
        const int row = m0 + wr * 64 + fm * 16 + lg * 4;
#pragma unroll
        for (int fn = 0; fn < 2; ++fn) {
            const int coln = n0 + wc * 32 + fn * 16 + l15;
            const float bsv = bias[coln];
#pragma unroll
            for (int r = 0; r < 4; ++r) {
                const int gr = row + r;
                if (gr >= M) continue;
                float v = acc[fm][fn][r] + bsv;
                if (RELU) v = fmaxf(v, 0.f);
                if (OUT_BF16)
                    ((__hip_bfloat16*)Cv)[(size_t)gr * ldc + col0 + coln] = __float2bfloat16(v);
                else
                    ((float*)Cv)[(size_t)gr * ldc + col0 + coln] = v;
            }
        }
    }
}

// ---------------------------------------------------------------------------
// Fused weight conversion fp32 -> bf16 into one packed buffer.
// ---------------------------------------------------------------------------
__global__ void cvt_weights(const float* w0, const float* w1, const float* w2,
                            const float* w3, const float* w4, const float* w5,
                            const float* w6, const float* w7, const float* w8,
                            const float* w9, __hip_bfloat16* dst) {
    int idx = blockIdx.x * 256 + threadIdx.x;
    float v;
    if      (idx <  196608) v = w0[idx];
    else if (idx <  262144) v = w1[idx -  196608];
    else if (idx <  458752) v = w2[idx -  262144];
    else if (idx <  524288) v = w3[idx -  458752];
    else if (idx <  589824) v = w4[idx -  524288];
    else if (idx <  622592) v = w5[idx -  589824];
    else if (idx <  688128) v = w6[idx -  622592];
    else if (idx <  753664) v = w7[idx -  688128];
    else if (idx < 1015808) v = w8[idx -  753664];
    else                    v = w9[idx - 1015808];
    dst[idx] = __float2bfloat16(v);
}

// ---------------------------------------------------------------------------
// Row gather (deform q order): dst[t] = X[r] + qpos[r], bf16.
// ---------------------------------------------------------------------------
__global__ void gather_rows_b(const float* __restrict__ src, const float* __restrict__ add,
                              __hip_bfloat16* __restrict__ dst) {
    int t = blockIdx.x, c = threadIdx.x;
    int b = t / 1700, jj = t % 1700;
    int q = jj / 17, p = jj % 17;
    int r = q * 136 + b * 17 + p;
    float v = src[(size_t)r * 256 + c] + add[(size_t)r * 256 + c];
    dst[(size_t)t * 256 + c] = __float2bfloat16(v);
}

// ---------------------------------------------------------------------------
// MHA S=17 (group attention). qkv bf16 rows t*768 (Q|K|V). block=(group, head)
// ---------------------------------------------------------------------------
__global__ void attn17(const __hip_bfloat16* __restrict__ qkv, __hip_bfloat16* __restrict__ out) {
    const int g = blockIdx.x, h = blockIdx.y;
    __shared__ float q[17][32], k[17][32], v[17][32], s[17][18];
    const int tid = threadIdx.x;  // 256
    for (int idx = tid; idx < 17 * 32; idx += 256) {
        int i = idx >> 5, d = idx & 31;
        size_t row = (size_t)(g * 17 + i) * 768 + h * 32 + d;
        q[i][d] = bs2f(*(const short*)&qkv[row]);
        k[i][d] = bs2f(*(const short*)&qkv[row + 256]);
        v[i][d] = bs2f(*(const short*)&qkv[row + 512]);
    }
    __syncthreads();
    for (int idx = tid; idx < 17 * 17; idx += 256) {
        int i = idx / 17, j = idx % 17;
        float acc = 0.f;
#pragma unroll
        for (int d = 0; d < 32; ++d) acc += q[i][d] * k[j][d];
        s[i][j] = acc * 0.17677669529663688f;
    }
    __syncthreads();
    if (tid < 17) {
        float m = -1e30f;
        for (int j = 0; j < 17; ++j) m = fmaxf(m, s[tid][j]);
        float sum = 0.f;
        for (int j = 0; j < 17; ++j) { float e = __expf(s[tid][j] - m); s[tid][j] = e; sum += e; }
        float inv = 1.f / sum;
        for (int j = 0; j < 17; ++j) s[tid][j] *= inv;
    }
    __syncthreads();
    for (int idx = tid; idx < 17 * 32; idx += 256) {
        int i = idx >> 5, d = idx & 31;
        float acc = 0.f;
        for (int j = 0; j < 17; ++j) acc += s[i][j] * v[j][d];
        out[(size_t)(g * 17 + i) * 256 + h * 32 + d] = __float2bfloat16(acc);
    }
}

// ---------------------------------------------------------------------------
// MHA S=100: thread-per-query online softmax, bf16 qkv input.
// ---------------------------------------------------------------------------
__global__ __launch_bounds__(128)
void attn100(const __hip_bfloat16* __restrict__ qkv, __hip_bfloat16* __restrict__ out) {
    const int g = blockIdx.x, h = blockIdx.y;
    __shared__ float Ks[100][32], Vs[100][32];
    const int tid = threadIdx.x;  // 128
    for (int idx = tid; idx < 800; idx += 128) {
        int j = idx >> 3, qd = (idx & 7) * 4;
        const __hip_bfloat16* base = qkv + (size_t)(g * 100 + j) * 768 + h * 32;
        bf16x4s kv = *(const bf16x4s*)(base + 256 + qd);
        bf16x4s vv = *(const bf16x4s*)(base + 512 + qd);
        Ks[j][qd] = bs2f(kv.x); Ks[j][qd+1] = bs2f(kv.y); Ks[j][qd+2] = bs2f(kv.z); Ks[j][qd+3] = bs2f(kv.w);
        Vs[j][qd] = bs2f(vv.x); Vs[j][qd+1] = bs2f(vv.y); Vs[j][qd+2] = bs2f(vv.z); Vs[j][qd+3] = bs2f(vv.w);
    }
    __syncthreads();
    if (tid >= 100) return;
    const __hip_bfloat16* qp = qkv + (size_t)(g * 100 + tid) * 768 + h * 32;
    float q[32];
#pragma unroll
    for (int d4 = 0; d4 < 32; d4 += 4) {
        bf16x4s v = *(const bf16x4s*)(qp + d4);
        q[d4] = bs2f(v.x); q[d4 + 1] = bs2f(v.y); q[d4 + 2] = bs2f(v.z); q[d4 + 3] = bs2f(v.w);
    }
    float m = -1e30f, l = 0.f, o[32];
#pragma unroll
    for (int d = 0; d < 32; ++d) o[d] = 0.f;
    for (int j = 0; j < 100; ++j) {
        float s = 0.f;
#pragma unroll
        for (int d = 0; d < 32; ++d) s += q[d] * Ks[j][d];
        s *= 0.17677669529663688f;
        float nm = fmaxf(m, s);
        float f = __expf(m - nm), p = __expf(s - nm);
        l = l * f + p;
#pragma unroll
        for (int d = 0; d < 32; ++d) o[d] = o[d] * f + p * Vs[j][d];
        m = nm;
    }
    float inv = 1.f / l;
    __hip_bfloat16* op = out + (size_t)(g * 100 + tid) * 256 + h * 32;
#pragma unroll
    for (int d = 0; d < 32; ++d) op[d] = __float2bfloat16(o[d] * inv);
}

// ---------------------------------------------------------------------------
// Deformable sampling: bf16 value input. block = 4 tokens, 256 threads.
// ---------------------------------------------------------------------------
#define TPB 4
__global__ __launch_bounds__(256)
void deform_sample(const __hip_bfloat16* __restrict__ value, const float* __restrict__ off,
                   const float* __restrict__ aw, const float* __restrict__ ref,
                   __hip_bfloat16* __restrict__ out) {
    const int t0 = blockIdx.x * TPB;
    const int tid = threadIdx.x;
    __shared__ float raw[TPB][128];
    __shared__ float wgt[TPB][128];
    __shared__ int   cidx[TPB][128][4];
    __shared__ float cw[TPB][128][4];

    for (int idx = tid; idx < TPB * 128; idx += 256) {
        int tk = idx >> 7, i = idx & 127;
        raw[tk][i] = aw[(size_t)(t0 + tk) * 128 + i];
    }
    __syncthreads();
    if (tid < TPB * 8) {
        int tk = tid >> 3, h = tid & 7;
        float m = -1e30f;
        for (int i = 0; i < 16; ++i) m = fmaxf(m, raw[tk][h * 16 + i]);
        float sum = 0.f;
        float e[16];
        for (int i = 0; i < 16; ++i) { e[i] = __expf(raw[tk][h * 16 + i] - m); sum += e[i]; }
        float inv = 1.f / sum;
        for (int i = 0; i < 16; ++i) wgt[tk][h * 16 + i] = e[i] * inv;
    }
    __syncthreads();

    const int Hs[4] = {92, 46, 23, 12};
    const int Sts[4] = {0, 8464, 10580, 11109};
    for (int s = tid; s < TPB * 128; s += 256) {
        int tk = s >> 7, sid = s & 127;
        int t = t0 + tk;
        int b = t / 1700, jj = t % 1700;
        int q = jj / 17, p = jj % 17;
        int l = (sid >> 2) & 3;
        int HW = Hs[l];
        float HWf = (float)HW;
        const float* refp = ref + (size_t)((q * 8 + b) * 17 + p) * 8;
        float rx = refp[l * 2], ry = refp[l * 2 + 1];
        float ox = off[(size_t)t * 256 + sid * 2];
        float oy = off[(size_t)t * 256 + sid * 2 + 1];
        float x = (rx + ox / HWf) * HWf - 0.5f;
        float y = (ry + oy / HWf) * HWf - 0.5f;
        float x0f = floorf(x), y0f = floorf(y);
        float wx = x - x0f, wy = y - y0f;
        int xi = (int)x0f, yi = (int)y0f;
        float wg = wgt[tk][sid];
#pragma unroll
        for (int c = 0; c < 4; ++c) {
            int cy = c >> 1, cx = c & 1;
            int yy = yi + cy, xx = xi + cx;
            bool ok = (xx >= 0) && (xx < HW) && (yy >= 0) && (yy < HW);
            int yc = min(max(yy, 0), HW - 1);
            int xc = min(max(xx, 0), HW - 1);
            cidx[tk][sid][c] = Sts[l] + yc * HW + xc;
            float w = (cy ? wy : 1.f - wy) * (cx ? wx : 1.f - wx);
            cw[tk][sid][c] = ok ? wg * w : 0.f;
        }
    }
    __syncthreads();

    const int tk = tid >> 6, lane = tid & 63;
    const int h = lane >> 3, d4 = (lane & 7) * 4;
    const int t = t0 + tk;
    const int b = t / 1700;
    const __hip_bfloat16* vb = value + (size_t)b * LENIN * 256 + h * 32 + d4;
    float4 acc = make_float4(0.f, 0.f, 0.f, 0.f);
    for (int s16 = 0; s16 < 16; ++s16) {
        int sid = h * 16 + s16;
#pragma unroll
        for (int c = 0; c < 4; ++c) {
            int idx = cidx[tk][sid][c];
            float w = cw[tk][sid][c];
            bf16x4s v = *(const bf16x4s*)(vb + (size_t)idx * 256);
            acc.x += w * bs2f(v.x); acc.y += w * bs2f(v.y);
            acc.z += w * bs2f(v.z); acc.w += w * bs2f(v.w);
        }
    }
    __hip_bfloat16* op = out + (size_t)t * 256 + h * 32 + d4;
    op[0] = __float2bfloat16(acc.x);
    op[1] = __float2bfloat16(acc.y);
    op[2] = __float2bfloat16(acc.z);
    op[3] = __float2bfloat16(acc.w);
}

// ---------------------------------------------------------------------------
// Residual + LayerNorm, one wave per row, shuffle reduce. proj is bf16.
// ---------------------------------------------------------------------------
__global__ __launch_bounds__(256)
void res_ln(const float* __restrict__ res, const __hip_bfloat16* __restrict__ proj,
            const float* __restrict__ g, const float* __restrict__ be,
            float* __restrict__ out, __hip_bfloat16* __restrict__ outb, int mode) {
    const int wave = threadIdx.x >> 6, lane = threadIdx.x & 63;
    const int r = blockIdx.x * 4 + wave;
    int t;
    if (mode == 0) t = r;
    else if (mode == 1) { int q = r / 136, m = r % 136; t = m * 100 + q; }
    else { int q = r / 136, rem = r % 136; int b = rem / 17, p = rem % 17; t = b * 1700 + q * 17 + p; }
    const int c4 = lane * 4;
    float4 a = *(const float4*)&res[(size_t)r * 256 + c4];
    bf16x4s pb = *(const bf16x4s*)&proj[(size_t)t * 256 + c4];
    float v[4] = {a.x + bs2f(pb.x), a.y + bs2f(pb.y), a.z + bs2f(pb.z), a.w + bs2f(pb.w)};
    float s = v[0] + v[1] + v[2] + v[3];
#pragma unroll
    for (int off = 32; off > 0; off >>= 1) s += __shfl_xor(s, off);
    float mean = s * (1.f / 256.f);
    float d[4], ss = 0.f;
#pragma unroll
    for (int i = 0; i < 4; ++i) { d[i] = v[i] - mean; ss += d[i] * d[i]; }
#pragma unroll
    for (int off = 32; off > 0; off >>= 1) ss += __shfl_xor(ss, off);
    float rs = rsqrtf(ss * (1.f / 256.f) + 1e-5f);
    float4 gv = *(const float4*)&g[c4];
    float4 bv = *(const float4*)&be[c4];
    float o0 = d[0] * rs * gv.x + bv.x;
    float o1 = d[1] * rs * gv.y + bv.y;
    float o2 = d[2] * rs * gv.z + bv.z;
    float o3 = d[3] * rs * gv.w + bv.w;
    *(float4*)&out[(size_t)r * 256 + c4] = make_float4(o0, o1, o2, o3);
    if (outb) {
        bf16x4s ob = {f2bs(o0), f2bs(o1), f2bs(o2), f2bs(o3)};
        *(bf16x4s*)&outb[(size_t)r * 256 + c4] = ob;
    }
}

// ---------------------------------------------------------------------------
extern "C" void kernel_launch(void* const* d_in, const int* in_sizes, int n_in,
                              void* d_out, int out_size, void* d_ws, size_t ws_size,
                              hipStream_t stream) {
    const float* tgt    = (const float*)d_in[0];
    const float* qpos   = (const float*)d_in[1];
    const float* ref    = (const float*)d_in[2];
    const float* memory = (const float*)d_in[3];
    const float* w_in_w = (const float*)d_in[4];
    const float* b_in_w = (const float*)d_in[5];
    const float* w_out_w= (const float*)d_in[6];
    const float* b_out_w= (const float*)d_in[7];
    const float* w_in_a = (const float*)d_in[8];
    const float* b_in_a = (const float*)d_in[9];
    const float* w_out_a= (const float*)d_in[10];
    const float* b_out_a= (const float*)d_in[11];
    const float* w_off  = (const float*)d_in[12];
    const float* b_off  = (const float*)d_in[13];
    const float* w_aw   = (const float*)d_in[14];
    const float* b_aw   = (const float*)d_in[15];
    const float* w_val  = (const float*)d_in[16];
    const float* b_val  = (const float*)d_in[17];
    const float* w_oc   = (const float*)d_in[18];
    const float* b_oc   = (const float*)d_in[19];
    const float* g_w    = (const float*)d_in[20];
    const float* be_w   = (const float*)d_in[21];
    const float* g_a    = (const float*)d_in[22];
    const float* be_a   = (const float*)d_in[23];
    const float* g1     = (const float*)d_in[24];
    const float* be1    = (const float*)d_in[25];
    const float* g2     = (const float*)d_in[26];
    const float* be2    = (const float*)d_in[27];
    const float* w1     = (const float*)d_in[28];
    const float* b1     = (const float*)d_in[29];
    const float* w2     = (const float*)d_in[30];
    const float* b2     = (const float*)d_in[31];

    float* X  = (float*)d_out;                       // persistent x, 13600x256 fp32
    float* ws = (float*)d_ws;
    float* R1 = ws;                                  // 23,046,144 f (qkv bf16 / value bf16 / H bf16)
    float* R2 = R1 + (size_t)MTOK * 256;             //  3,481,600 f (off fp32 / proj bf16)
    float* R3 = R2 + (size_t)NTOK * 256;             //  1,740,800 f (bf16 attn/deform outs)
    float* R6 = R3 + (size_t)NTOK * 128;             //  1,740,800 f (raw attn weights fp32)
    float* QBF= R6 + (size_t)NTOK * 128;             //  1,740,800 f (bf16 deform-q / ffn in)
    float* WBF= QBF+ (size_t)NTOK * 128;             //    638,976 f (packed bf16 weights)

    __hip_bfloat16* R1b = (__hip_bfloat16*)R1;
    __hip_bfloat16* R2b = (__hip_bfloat16*)R2;
    __hip_bfloat16* R3b = (__hip_bfloat16*)R3;
    __hip_bfloat16* Qb  = (__hip_bfloat16*)QBF;
    __hip_bfloat16* Wb  = (__hip_bfloat16*)WBF;
    __hip_bfloat16* Hb  = (__hip_bfloat16*)R1;       // ffn hidden alias
    __hip_bfloat16* Vb  = (__hip_bfloat16*)R1;       // value alias

    __hip_bfloat16* w_in_w_b  = Wb;                  // 768x256
    __hip_bfloat16* w_out_w_b = Wb +  196608;        // 256x256
    __hip_bfloat16* w_in_a_b  = Wb +  262144;        // 768x256
    __hip_bfloat16* w_out_a_b = Wb +  458752;        // 256x256
    __hip_bfloat16* w_off_b   = Wb +  524288;        // 256x256
    __hip_bfloat16* w_aw_b    = Wb +  589824;        // 128x256
    __hip_bfloat16* w_val_b   = Wb +  622592;        // 256x256
    __hip_bfloat16* w_oc_b    = Wb +  688128;        // 256x256
    __hip_bfloat16* w1_b      = Wb +  753664;        // 1024x256
    __hip_bfloat16* w2_b      = Wb + 1015808;        // 256x1024

    cvt_weights<<<4992, 256, 0, stream>>>(w_in_w, w_out_w, w_in_a, w_out_a, w_off,
                                          w_aw, w_val, w_oc, w1, w2, Wb);

    const int MY = (NTOK + 127) / 128;   // 107

    // ---- Phase 1: fused QKV projection (QK: tgt+qpos, V: tgt) ----
    gemm_mfma<2, false, true><<<dim3(6, MY), 512, 0, stream>>>(
        tgt, qpos, w_in_w_b, b_in_w, R1b, NTOK, 768, 256, 768, 0, 2);
    attn17<<<dim3(800, 8), 256, 0, stream>>>(R1b, R3b);
    gemm_mfma<0, false, true><<<dim3(2, MY), 512, 0, stream>>>(
        R3b, nullptr, w_out_w_b, b_out_w, R2b, NTOK, 256, 256, 256, 0, 0);
    res_ln<<<NTOK / 4, 256, 0, stream>>>(tgt, R2b, g_w, be_w, X, nullptr, 0);

    // ---- Phase 2: query attention, gather fused (y-order A-map) ----
    gemm_mfma<3, false, true><<<dim3(6, MY), 512, 0, stream>>>(
        X, nullptr, w_in_a_b, b_in_a, R1b, NTOK, 768, 256, 768, 0, 0);
    attn100<<<dim3(136, 8), 128, 0, stream>>>(R1b, R3b);
    gemm_mfma<0, false, true><<<dim3(2, MY), 512, 0, stream>>>(
        R3b, nullptr, w_out_a_b, b_out_a, R2b, NTOK, 256, 256, 256, 0, 0);
    res_ln<<<NTOK / 4, 256, 0, stream>>>(X, R2b, g_a, be_a, X, nullptr, 1);

    // ---- Phase 3: deformable attention ----
    gemm_mfma<1, false, true><<<dim3(2, (MTOK + 127) / 128), 512, 0, stream>>>(
        memory, nullptr, w_val_b, b_val, Vb, MTOK, 256, 256, 256, 0, 0);
    gather_rows_b<<<NTOK, 256, 0, stream>>>(X, qpos, Qb);
    gemm_mfma<0, false, false><<<dim3(2, MY), 512, 0, stream>>>(
        Qb, nullptr, w_off_b, b_off, R2, NTOK, 256, 256, 256, 0, 0);
    gemm_mfma<0, false, false><<<dim3(1, MY), 512, 0, stream>>>(
        Qb, nullptr, w_aw_b, b_aw, R6, NTOK, 128, 256, 128, 0, 0);
    deform_sample<<<NTOK / TPB, 256, 0, stream>>>(Vb, R2, R6, ref, R3b);
    gemm_mfma<0, false, true><<<dim3(2, MY), 512, 0, stream>>>(
        R3b, nullptr, w_oc_b, b_oc, R2b, NTOK, 256, 256, 256, 0, 0);
    res_ln<<<NTOK / 4, 256, 0, stream>>>(X, R2b, g1, be1, X, Qb, 2);

    // ---- Phase 4: FFN ----
    gemm_mfma<0, true, true><<<dim3(8, MY), 512, 0, stream>>>(
        Qb, nullptr, w1_b, b1, Hb, NTOK, 1024, 256, 1024, 0, 0);
    gemm_mfma<0, false, true><<<dim3(2, MY), 512, 0, stream>>>(
        Hb, nullptr, w2_b, b2, R2b, NTOK, 256, 1024, 256, 0, 0);
    res_ln<<<NTOK / 4, 256, 0, stream>>>(X, R2b, g2, be2, X, nullptr, 0);
}